// Round 6
// baseline (335.263 us; speedup 1.0000x reference)
//
#include <hip/hip_runtime.h>

// SNN: 2-layer LIF, T=4096, B=1024, 6->10->27.
// Round 6: TWO batch elements per wave (elem A = lanes 0-31, elem B = lanes 32-63).
//   512 blocks x 128 threads (wave 0 + wave 1) = 1024 waves = 1/SIMD.
//   wave 0: cur1 precompute (2 passes x 32 steps, lane=(half,step)) + DUAL mem1 chain
//           (lanes h*32+i = elem h neuron i); ballot gives both masks in one 64-bit
//           SGPR -> pack 20 bits, capture via lane-select; 1 ds_write/chunk.
//   wave 1: lag-1; broadcast-reads packed masks (b128 x2 per 8 steps), per-lane bfe
//           row extract, 2 table reads/step (2-way bank = free), DUAL mem2 chain.
//   Gather feeds chain in-register (no cur2Buf -> no scatter bank conflicts).
// Per-element arithmetic identical to rounds 1-5 (absmax 0.0).

#define T_STEPS 4096
#define BETA 0.9f
#define THRESH 1.0f
#define CH 64
#define NCHUNK (T_STEPS / CH)   // 64
#define GRP 8
#define NGRP (CH / GRP)

__global__ __launch_bounds__(128, 1) void snn_kernel(
    const float* __restrict__ x,   // [B][6][T]
    const float* __restrict__ W1,  // [10][6]
    const float* __restrict__ b1,  // [10]
    const float* __restrict__ W2,  // [27][10]
    const float* __restrict__ b2,  // [27]
    float* __restrict__ out)       // [B][27]
{
    __shared__ float tabLo[32 * 32];     // [m][j]: b2[j] + sum_{i<5} bit_i(m)*W2[j][i]
    __shared__ float tabHi[32 * 32];     // [m][j]: sum_{i<5} bit_i(m)*W2[j][5+i]
    __shared__ float curBuf[20 * 68];    // [half*10+neuron][t 0..63 (+4 pad)]
    __shared__ unsigned maskBuf[2][64];  // [parity][t]: bits 0-9 elem A, 10-19 elem B

    const int tid = threadIdx.x;
    const int wid = tid >> 6;
    const int l   = tid & 63;
    const int h   = l >> 5;        // which element of the pair
    const int li  = l & 31;
    const int b   = blockIdx.x;
    const int e   = 2 * b + h;     // this lane's batch element

    // ---- layer-2 lookup tables (identical construction to rounds 1-5) ----
    if (tid < 32) {
        for (int j = 0; j < 27; ++j) {
            float slo = b2[j];
            float shi = 0.0f;
            #pragma unroll
            for (int i = 0; i < 5; ++i) {
                if (tid & (1 << i)) {
                    slo += W2[j * 10 + i];
                    shi += W2[j * 10 + 5 + i];
                }
            }
            tabLo[tid * 32 + j] = slo;
            tabHi[tid * 32 + j] = shi;
        }
    }

    // ---- wave-0 state ----
    float w1r[60], b1r[10];
    float xv[2][6], xn[2][6];            // [pass][channel], pass = 32-step half of chunk
    float mem1 = 0.0f;
    bool  sp1 = false;
    const int ri = (li < 10) ? li : 9;   // neuron owned in the chain (shadows clamp)
    const float* cp = &curBuf[(h * 10 + ri) * 68];
    const float* xb = x + (size_t)e * 6 * T_STEPS;

    if (wid == 0) {
        #pragma unroll
        for (int i = 0; i < 10; ++i) {
            b1r[i] = b1[i];
            #pragma unroll
            for (int c = 0; c < 6; ++c) w1r[i * 6 + c] = W1[i * 6 + c];
        }
        #pragma unroll
        for (int p = 0; p < 2; ++p)
            #pragma unroll
            for (int c = 0; c < 6; ++c) xv[p][c] = xb[c * T_STEPS + p * 32 + li];
    }

    // ---- wave-1 state ----
    float mem2 = 0.0f;
    bool  sp2 = false;
    const int jc = (li < 27) ? li : 26;  // output neuron (shadows clamp)
    const int ofsLo = h * 10;            // bit offset of this element's low 5 mask bits
    const int ofsHi = h * 10 + 5;

    __syncthreads();

    #pragma unroll 1
    for (int k = 0; k <= NCHUNK; ++k) {
        // ================= wave 0: layer 1, chunk k, both elements =================
        if (wid == 0 && k < NCHUNK) {
            // cur1 precompute: pass p covers steps p*32 + li of this lane's element
            #pragma unroll
            for (int p = 0; p < 2; ++p) {
                #pragma unroll
                for (int i = 0; i < 10; ++i) {
                    float acc = xv[p][0] * w1r[i * 6 + 0];
                    acc = fmaf(xv[p][1], w1r[i * 6 + 1], acc);
                    acc = fmaf(xv[p][2], w1r[i * 6 + 2], acc);
                    acc = fmaf(xv[p][3], w1r[i * 6 + 3], acc);
                    acc = fmaf(xv[p][4], w1r[i * 6 + 4], acc);
                    acc = fmaf(xv[p][5], w1r[i * 6 + 5], acc);
                    curBuf[(h * 10 + i) * 68 + p * 32 + li] = acc + b1r[i];
                }
            }
            // prefetch next chunk's x
            if (k + 1 < NCHUNK) {
                #pragma unroll
                for (int p = 0; p < 2; ++p)
                    #pragma unroll
                    for (int c = 0; c < 6; ++c)
                        xn[p][c] = xb[c * T_STEPS + (k + 1) * CH + p * 32 + li];
            }

            // dual mem1 chain: one fma/cndmask/cmp serves both elements
            unsigned vmask = 0u;   // lane t accumulates packed mask[t]
            float c1v[8];
            {
                float4 q0 = *(const float4*)(cp + 0);
                float4 q1 = *(const float4*)(cp + 4);
                c1v[0] = q0.x; c1v[1] = q0.y; c1v[2] = q0.z; c1v[3] = q0.w;
                c1v[4] = q1.x; c1v[5] = q1.y; c1v[6] = q1.z; c1v[7] = q1.w;
            }
            #pragma unroll
            for (int g = 0; g < NGRP; ++g) {
                float c1n[8];
                if (g + 1 < NGRP) {
                    float4 p0 = *(const float4*)(cp + (g + 1) * 8);
                    float4 p1 = *(const float4*)(cp + (g + 1) * 8 + 4);
                    c1n[0] = p0.x; c1n[1] = p0.y; c1n[2] = p0.z; c1n[3] = p0.w;
                    c1n[4] = p1.x; c1n[5] = p1.y; c1n[6] = p1.z; c1n[7] = p1.w;
                }
                #pragma unroll
                for (int s = 0; s < 8; ++s) {
                    float t1 = fmaf(BETA, mem1, c1v[s]);
                    mem1 = sp1 ? (t1 - THRESH) : t1;            // == t1 - rst*THRESH
                    sp1 = mem1 > THRESH;
                    unsigned long long bal = __ballot(sp1);     // SGPR pair, both elems
                    unsigned mC = (unsigned)((bal & 0x3FFull) |
                                             ((bal >> 22) & 0xFFC00ull));  // SALU pack
                    vmask = (l == g * 8 + s) ? mC : vmask;      // lane-select capture
                }
                if (g + 1 < NGRP) {
                    #pragma unroll
                    for (int s = 0; s < 8; ++s) c1v[s] = c1n[s];
                }
            }
            maskBuf[k & 1][l] = vmask;

            if (k + 1 < NCHUNK) {
                #pragma unroll
                for (int p = 0; p < 2; ++p)
                    #pragma unroll
                    for (int c = 0; c < 6; ++c) xv[p][c] = xn[p][c];
            }
        }

        // ============ wave 1: layer 2, chunk k-1, both elements ============
        if (wid == 1 && k >= 1) {
            const unsigned* mrow = maskBuf[(k - 1) & 1];

            // group-pipelined: masks (broadcast b128 x2) -> rows (bfe) -> 2 tab reads/step
            float tlo[8], thi[8];
            {
                uint4 m0 = *(const uint4*)(mrow + 0);
                uint4 m1 = *(const uint4*)(mrow + 4);
                unsigned mv[8] = {m0.x, m0.y, m0.z, m0.w, m1.x, m1.y, m1.z, m1.w};
                #pragma unroll
                for (int s = 0; s < 8; ++s) {
                    unsigned rl = (mv[s] >> ofsLo) & 31u;
                    unsigned rh = (mv[s] >> ofsHi) & 31u;
                    tlo[s] = tabLo[rl * 32 + jc];
                    thi[s] = tabHi[rh * 32 + jc];
                }
            }
            #pragma unroll
            for (int g = 0; g < NGRP; ++g) {
                float ntl[8], nth[8];
                if (g + 1 < NGRP) {
                    uint4 m0 = *(const uint4*)(mrow + (g + 1) * 8);
                    uint4 m1 = *(const uint4*)(mrow + (g + 1) * 8 + 4);
                    unsigned mv[8] = {m0.x, m0.y, m0.z, m0.w, m1.x, m1.y, m1.z, m1.w};
                    #pragma unroll
                    for (int s = 0; s < 8; ++s) {
                        unsigned rl = (mv[s] >> ofsLo) & 31u;
                        unsigned rh = (mv[s] >> ofsHi) & 31u;
                        ntl[s] = tabLo[rl * 32 + jc];
                        nth[s] = tabHi[rh * 32 + jc];
                    }
                }
                #pragma unroll
                for (int s = 0; s < 8; ++s) {
                    float cur2 = tlo[s] + thi[s];       // b2 folded into tabLo
                    float t2 = fmaf(BETA, mem2, cur2);
                    mem2 = sp2 ? (t2 - THRESH) : t2;
                    sp2 = mem2 > THRESH;
                }
                if (g + 1 < NGRP) {
                    #pragma unroll
                    for (int s = 0; s < 8; ++s) { tlo[s] = ntl[s]; thi[s] = nth[s]; }
                }
            }
        }

        __syncthreads();   // uniform: both waves, every iteration
    }

    if (wid == 1 && li < 27) {
        out[e * 27 + li] = sp2 ? 1.0f : 0.0f;
    }
}

extern "C" void kernel_launch(void* const* d_in, const int* in_sizes, int n_in,
                              void* d_out, int out_size, void* d_ws, size_t ws_size,
                              hipStream_t stream) {
    const float* x  = (const float*)d_in[0];
    const float* W1 = (const float*)d_in[1];
    const float* b1 = (const float*)d_in[2];
    const float* W2 = (const float*)d_in[3];
    const float* b2 = (const float*)d_in[4];
    float* out = (float*)d_out;

    const int B = in_sizes[0] / (6 * T_STEPS);  // 1024
    snn_kernel<<<dim3(B / 2), dim3(128), 0, stream>>>(x, W1, b1, W2, b2, out);
}